// Round 5
// baseline (1469.793 us; speedup 1.0000x reference)
//
#include <hip/hip_runtime.h>
#include <hip/hip_bf16.h>
#include <stdint.h>

// Problem constants: B=2, S=1024 -> T=2048; D=1024; E=8; F=4*D=4096
#define DDIM 1024
#define EXP 8
#define FDIM 4096

typedef __attribute__((ext_vector_type(8))) short short8v;
typedef __attribute__((ext_vector_type(8))) short bf16x8;
typedef __attribute__((ext_vector_type(4))) float f32x4;

__device__ __forceinline__ unsigned short f2bf(float f) {
    unsigned u = __float_as_uint(f);
    u += 0x7FFFu + ((u >> 16) & 1u);          // round-to-nearest-even
    return (unsigned short)(u >> 16);
}
__device__ __forceinline__ float bf2f(unsigned short h) {
    return __uint_as_float(((unsigned)h) << 16);
}

// ---------------------------------------------------------------------------
// Packed operand format (R x K fp32 -> hi/lo bf16), tile = 128 rows x 32 k
// = 16 KiB. Within a tile: row_local rl (128B each); 8 slots of 16B per row:
// logical slots 0-3 = hi k8-groups, 4-7 = lo; stored slot = logical^(rl&7)
// (XOR bank swizzle; 2-way max on ds_read_b128 = free, m136). Linear byte
// order of a tile == the LDS image global_load_lds produces (identity map).
// ---------------------------------------------------------------------------

// Pack x [T][D] -> Xp. One thread per (row, k8-group).
__global__ __launch_bounds__(256) void packx_kernel(
    const float* __restrict__ x, char* __restrict__ Xp, int T)
{
    int idx = blockIdx.x * 256 + threadIdx.x;
    int r = idx >> 7;              // D/8 = 128 k8-groups per row
    int k8 = idx & 127;
    if (r >= T) return;
    const float* src = x + (size_t)r * DDIM + k8 * 8;
    float4 v0 = *(const float4*)(src);
    float4 v1 = *(const float4*)(src + 4);
    float f[8] = {v0.x, v0.y, v0.z, v0.w, v1.x, v1.y, v1.z, v1.w};
    short8v h8, l8;
#pragma unroll
    for (int i = 0; i < 8; ++i) {
        unsigned short hh = f2bf(f[i]);
        h8[i] = (short)hh;
        l8[i] = (short)f2bf(f[i] - bf2f(hh));
    }
    int kb = k8 >> 2, k8l = k8 & 3, rl = r & 127, rb = r >> 7;
    size_t tb = ((size_t)(rb * (DDIM >> 5) + kb)) << 14;
    char* dst = Xp + tb + (rl << 7);
    int sh = (k8l ^ (rl & 7)) << 4;            // hi slot
    *(short8v*)(dst + sh) = h8;
    *(short8v*)(dst + (sh ^ 64)) = l8;         // lo slot = hi ^ 4 -> byte ^ 64
}

// Pack+transpose W [E][K][N] (k-major) -> Wp per expert as B-format [N][K].
// grid (Ktiles, Ntiles, E); one block per 32k x 128n tile.
__global__ __launch_bounds__(256) void packw_kernel(
    const float* __restrict__ W, char* __restrict__ Wp, int K, int N)
{
    int kb = blockIdx.x, nb = blockIdx.y, e = blockIdx.z;
    int t = threadIdx.x;
    int Ktiles = K >> 5;
    __shared__ float lds[32][132];             // +4 pad: phase-2 reads 2-way max
    const float* src = W + (size_t)e * K * N + (size_t)(kb * 32) * N + nb * 128;
#pragma unroll
    for (int j = 0; j < 4; ++j) {
        int idx = t + j * 256;
        int kk = idx >> 5, c4 = idx & 31;      // 32 float4 per 128-wide row
        float4 v = *(const float4*)(src + (size_t)kk * N + c4 * 4);
        *(float4*)&lds[kk][c4 * 4] = v;
    }
    __syncthreads();
    int n = t >> 1, pair = t & 1;
    char* dstrow = Wp + (size_t)e * ((size_t)N * K * 4)
                 + (((size_t)(nb * Ktiles + kb)) << 14) + (n << 7);
    int nx = n & 7;
#pragma unroll
    for (int q = 0; q < 2; ++q) {
        int k8 = pair * 2 + q;
        short8v h8, l8;
#pragma unroll
        for (int i = 0; i < 8; ++i) {
            float f = lds[k8 * 8 + i][n];
            unsigned short hh = f2bf(f);
            h8[i] = (short)hh;
            l8[i] = (short)f2bf(f - bf2f(hh));
        }
        int sh = (k8 ^ nx) << 4;
        *(short8v*)(dstrow + sh) = h8;
        *(short8v*)(dstrow + (sh ^ 64)) = l8;
    }
}

// ---------------------------------------------------------------------------
// Router: logits + alpha-entmax(1.5) bisection + threshold. One block/token.
// ---------------------------------------------------------------------------
__global__ __launch_bounds__(256) void router_kernel(
    const float* __restrict__ x, const float* __restrict__ Wr,
    const float* __restrict__ br, float* __restrict__ gates)
{
    const int t = blockIdx.x;
    const int tid = threadIdx.x;
    const float* xr = x + (size_t)t * DDIM;

    float acc[EXP];
#pragma unroll
    for (int e = 0; e < EXP; ++e) acc[e] = 0.f;
    for (int d = tid; d < DDIM; d += 256) {
        float xv = xr[d];
        const float* wr = Wr + (size_t)d * EXP;
#pragma unroll
        for (int e = 0; e < EXP; ++e) acc[e] += xv * wr[e];
    }
#pragma unroll
    for (int e = 0; e < EXP; ++e) {
        float v = acc[e];
#pragma unroll
        for (int off = 32; off > 0; off >>= 1) v += __shfl_down(v, off);
        acc[e] = v;
    }
    __shared__ float part[4][EXP];
    const int wave = tid >> 6, lane = tid & 63;
    if (lane == 0) {
#pragma unroll
        for (int e = 0; e < EXP; ++e) part[wave][e] = acc[e];
    }
    __syncthreads();

    if (tid == 0) {
        float Xs[EXP];
        float mx = -1e30f;
#pragma unroll
        for (int e = 0; e < EXP; ++e) {
            float lg = part[0][e] + part[1][e] + part[2][e] + part[3][e] + br[e];
            Xs[e] = 0.5f * lg;                          // *(alpha-1), TEMP=1
            mx = fmaxf(mx, Xs[e]);
        }
        float tau_lo = mx - 1.0f;
        const float tau_hi = mx - 0.35355339059327373f; // (1/8)^0.5
        float f_lo = -1.0f;
#pragma unroll
        for (int e = 0; e < EXP; ++e) {
            float u = fmaxf(Xs[e] - tau_lo, 0.f);
            f_lo += u * u;                              // inv_am1 = 2
        }
        float dm = tau_hi - tau_lo;
        float tau_m = tau_lo;
        for (int it = 0; it < 25; ++it) {
            dm *= 0.5f;
            tau_m = tau_lo + dm;
            float f_m = -1.0f;
#pragma unroll
            for (int e = 0; e < EXP; ++e) {
                float u = fmaxf(Xs[e] - tau_m, 0.f);
                f_m += u * u;
            }
            if (f_m * f_lo >= 0.f) tau_lo = tau_m;
        }
        float p[EXP], s = 0.f;
#pragma unroll
        for (int e = 0; e < EXP; ++e) {
            float u = fmaxf(Xs[e] - tau_m, 0.f);
            p[e] = u * u;
            s += p[e];
        }
        float inv = 1.f / s;
#pragma unroll
        for (int e = 0; e < EXP; ++e) {
            float g = p[e] * inv;
            gates[(size_t)t * EXP + e] = (g > 1e-9f) ? g : 0.f;
        }
    }
}

// ---------------------------------------------------------------------------
// Packed-operand split-bf16 MFMA GEMM. 128x128 tile, BK=32, 4 waves (2x2),
// wave-tile 64x64 (4x4 16x16x32 frags), 3 products (ah*bh + ah*bl + al*bh).
// Staging: pure global_load_lds dwordx4 (tile bytes are the LDS image).
// EPI=1: H = split(relu(C + b1)*gate) written in packed-A format for GEMM2.
// EPI=2: P[e][m][d] = C (fp32 partial).
// 1-D grid with bijective XCD chunking; mb fastest (EPI=1) / nb fastest (EPI=2).
// ---------------------------------------------------------------------------
template<int EPI>
__global__ __launch_bounds__(256) void gemm_pk(
    const char* __restrict__ Ap, size_t a_es, int arb0,
    const char* __restrict__ Bp, size_t b_es,
    int Ktiles, int Mb, int Nb,
    const float* __restrict__ bias, const float* __restrict__ gates,
    char* __restrict__ Hout, float* __restrict__ Pout,
    int CT, int t0)
{
    __shared__ char sA[16384];
    __shared__ char sB[16384];

    const int tid = threadIdx.x;
    const int lane = tid & 63;
    const int wid = tid >> 6;
    const int wr = wid >> 1, wc = wid & 1;
    const int lr = lane & 15, lg = lane >> 4;
    const int rx = lr & 7;

    // bijective XCD swizzle (nwg % 8 == 0 always: Nb*EXP multiple of 8)
    int bI = blockIdx.x;
    int nwg = Mb * Nb * EXP;
    int cpx = nwg >> 3;
    int w = (bI & 7) * cpx + (bI >> 3);
    int e = w / (Mb * Nb);
    int rem = w - e * (Mb * Nb);
    int mb, nb;
    if (EPI == 1) { nb = rem / Mb; mb = rem - nb * Mb; }   // mb fastest: share B panel
    else          { mb = rem / Nb; nb = rem - mb * Nb; }   // nb fastest: share A panel

    const char* Abase = Ap + (size_t)e * a_es + (((size_t)(arb0 + mb) * Ktiles) << 14);
    const char* Bbase = Bp + (size_t)e * b_es + (((size_t)nb * Ktiles) << 14);

    f32x4 acc[4][4];
#pragma unroll
    for (int mi = 0; mi < 4; ++mi)
#pragma unroll
        for (int ni = 0; ni < 4; ++ni) acc[mi][ni] = (f32x4){0.f, 0.f, 0.f, 0.f};

    // fragment byte offsets (hi plane); lo plane = ^64
    int aoff[4], boff[4];
#pragma unroll
    for (int mi = 0; mi < 4; ++mi)
        aoff[mi] = (wr * 64 + mi * 16 + lr) * 128 + ((lg ^ rx) << 4);
#pragma unroll
    for (int ni = 0; ni < 4; ++ni)
        boff[ni] = (wc * 64 + ni * 16 + lr) * 128 + ((lg ^ rx) << 4);

    const int stg = (wid << 12) + (lane << 4);
    const int ldst = wid << 12;

    for (int kb = 0; kb < Ktiles; ++kb) {
        const char* at = Abase + ((size_t)kb << 14) + stg;
        const char* bt = Bbase + ((size_t)kb << 14) + stg;
        __syncthreads();                        // prior compute done; LDS reusable
#pragma unroll
        for (int j = 0; j < 4; ++j) {
            __builtin_amdgcn_global_load_lds(
                (const __attribute__((address_space(1))) void*)(at + j * 1024),
                (__attribute__((address_space(3))) void*)(sA + ldst + j * 1024),
                16, 0, 0);
            __builtin_amdgcn_global_load_lds(
                (const __attribute__((address_space(1))) void*)(bt + j * 1024),
                (__attribute__((address_space(3))) void*)(sB + ldst + j * 1024),
                16, 0, 0);
        }
        __syncthreads();                        // compiler drains vmcnt(0) here

        bf16x8 ah[4], al[4];
#pragma unroll
        for (int mi = 0; mi < 4; ++mi) {
            ah[mi] = *(const bf16x8*)(sA + aoff[mi]);
            al[mi] = *(const bf16x8*)(sA + (aoff[mi] ^ 64));
        }
#pragma unroll
        for (int ni = 0; ni < 4; ++ni) {
            bf16x8 bh = *(const bf16x8*)(sB + boff[ni]);
            bf16x8 bl = *(const bf16x8*)(sB + (boff[ni] ^ 64));
#pragma unroll
            for (int mi = 0; mi < 4; ++mi) {
                acc[mi][ni] = __builtin_amdgcn_mfma_f32_16x16x32_bf16(ah[mi], bh, acc[mi][ni], 0, 0, 0);
                acc[mi][ni] = __builtin_amdgcn_mfma_f32_16x16x32_bf16(ah[mi], bl, acc[mi][ni], 0, 0, 0);
                acc[mi][ni] = __builtin_amdgcn_mfma_f32_16x16x32_bf16(al[mi], bh, acc[mi][ni], 0, 0, 0);
            }
        }
    }

    const int m0 = mb * 128, n0 = nb * 128;
    // C/D layout (m89-verified): col = lane&15, row = (lane>>4)*4 + reg.
    if (EPI == 1) {
        char* He = Hout + (size_t)e * ((size_t)CT * FDIM * 4);
        float garr[4][4];
#pragma unroll
        for (int mi = 0; mi < 4; ++mi)
#pragma unroll
            for (int r = 0; r < 4; ++r)
                garr[mi][r] = gates[(size_t)(t0 + m0 + wr * 64 + mi * 16 + lg * 4 + r) * EXP + e];
#pragma unroll
        for (int ni = 0; ni < 4; ++ni) {
            const int f = n0 + wc * 64 + ni * 16 + lr;
            const float bv = bias[e * FDIM + f];
            const int fb = f >> 5, kl = f & 31;
#pragma unroll
            for (int mi = 0; mi < 4; ++mi) {
#pragma unroll
                for (int r = 0; r < 4; ++r) {
                    int mrow = m0 + wr * 64 + mi * 16 + lg * 4 + r;
                    float v = fmaxf(acc[mi][ni][r] + bv, 0.f) * garr[mi][r];
                    unsigned short hh = f2bf(v);
                    unsigned short ll = f2bf(v - bf2f(hh));
                    int rl = mrow & 127;
                    size_t tb = ((size_t)((mrow >> 7) * (FDIM >> 5) + fb)) << 14;
                    char* pa = He + tb + (rl << 7) + ((kl & 7) << 1);
                    int sh = (((kl >> 3) ^ (rl & 7)) << 4);
                    *(unsigned short*)(pa + sh) = hh;
                    *(unsigned short*)(pa + (sh ^ 64)) = ll;
                }
            }
        }
    } else {
#pragma unroll
        for (int mi = 0; mi < 4; ++mi) {
#pragma unroll
            for (int ni = 0; ni < 4; ++ni) {
                const int col = n0 + wc * 64 + ni * 16 + lr;
#pragma unroll
                for (int r = 0; r < 4; ++r) {
                    int mrow = m0 + wr * 64 + mi * 16 + lg * 4 + r;
                    Pout[((size_t)e * CT + mrow) * DDIM + col] = acc[mi][ni][r];
                }
            }
        }
    }
}

// ---------------------------------------------------------------------------
// out[t0+m][d] = sum_e ( P[e][m][d] + gate[t][e]*b2[e][d] )
// ---------------------------------------------------------------------------
__global__ __launch_bounds__(256) void reduce_kernel(
    const float* __restrict__ P, const float* __restrict__ gates,
    const float* __restrict__ b2, float* __restrict__ out, int t0, int CT)
{
    int i = blockIdx.x * 256 + threadIdx.x;    // float4 idx within chunk
    int m = i >> 8, d4 = i & 255;              // DDIM/4 = 256
    if (m >= CT) return;
    int t = t0 + m;
    float4 s = {0.f, 0.f, 0.f, 0.f};
#pragma unroll
    for (int e = 0; e < EXP; ++e) {
        float g = gates[(size_t)t * EXP + e];
        float4 p = ((const float4*)P)[((size_t)e * CT + m) * 256 + d4];
        float4 bb = ((const float4*)b2)[e * 256 + d4];
        s.x += p.x + g * bb.x;
        s.y += p.y + g * bb.y;
        s.z += p.z + g * bb.z;
        s.w += p.w + g * bb.w;
    }
    ((float4*)out)[(size_t)t * 256 + d4] = s;
}

// ---------------------------------------------------------------------------
extern "C" void kernel_launch(void* const* d_in, const int* in_sizes, int n_in,
                              void* d_out, int out_size, void* d_ws, size_t ws_size,
                              hipStream_t stream)
{
    const float* x  = (const float*)d_in[0];
    const float* Wr = (const float*)d_in[1];
    const float* br = (const float*)d_in[2];
    const float* W1 = (const float*)d_in[3];
    const float* b1 = (const float*)d_in[4];
    const float* W2 = (const float*)d_in[5];
    const float* b2 = (const float*)d_in[6];
    float* out = (float*)d_out;

    const int T = in_sizes[0] / DDIM;   // 2048

    char* p = (char*)d_ws;
    size_t used = 0;
    auto carve = [&](size_t bytes) {
        char* r = p + used;
        used += (bytes + 255) & ~(size_t)255;
        return r;
    };
    float* gates = (float*)carve((size_t)T * EXP * 4);
    char*  Xp    = carve((size_t)T * DDIM * 4);
    char*  W1p   = carve((size_t)EXP * DDIM * FDIM * 4);
    char*  W2p   = carve((size_t)EXP * FDIM * DDIM * 4);

    const size_t per_tok = (size_t)EXP * FDIM * 4 + (size_t)EXP * DDIM * 4;
    int CT = 128;
    for (int c = 2048; c >= 128; c >>= 1)
        if (used + (size_t)c * per_tok + 1024 <= ws_size) { CT = c; break; }
    if (CT > T) CT = T;
    char*  Hp = carve((size_t)EXP * CT * FDIM * 4);
    float* Pp = (float*)carve((size_t)EXP * CT * DDIM * 4);

    // ---- pack passes ----
    packx_kernel<<<dim3((T * (DDIM / 8) + 255) / 256), dim3(256), 0, stream>>>(x, Xp, T);
    packw_kernel<<<dim3(DDIM / 32, FDIM / 128, EXP), dim3(256), 0, stream>>>(W1, W1p, DDIM, FDIM);
    packw_kernel<<<dim3(FDIM / 32, DDIM / 128, EXP), dim3(256), 0, stream>>>(W2, W2p, FDIM, DDIM);
    router_kernel<<<dim3(T), dim3(256), 0, stream>>>(x, Wr, br, gates);

    const size_t w_es = (size_t)DDIM * FDIM * 4;   // 16 MiB per expert (both W)
    for (int t0 = 0; t0 < T; t0 += CT) {
        int Mb = CT / 128;
        // GEMM1: A=Xp (R=T,K=D), B=W1p (R=F,K=D) -> H packed
        gemm_pk<1><<<dim3(Mb * (FDIM / 128) * EXP), dim3(256), 0, stream>>>(
            Xp, (size_t)0, t0 >> 7, W1p, w_es, DDIM / 32, Mb, FDIM / 128,
            b1, gates, Hp, (float*)nullptr, CT, t0);
        // GEMM2: A=Hp (R=CT,K=F per expert), B=W2p (R=D,K=F) -> P fp32
        gemm_pk<2><<<dim3(Mb * (DDIM / 128) * EXP), dim3(256), 0, stream>>>(
            Hp, (size_t)CT * FDIM * 4, 0, W2p, w_es, FDIM / 32, Mb, DDIM / 128,
            (const float*)nullptr, gates, (char*)nullptr, Pp, CT, t0);
        reduce_kernel<<<dim3(CT), dim3(256), 0, stream>>>(Pp, gates, b2, out, t0, CT);
    }
}

// Round 7
// 1146.075 us; speedup vs baseline: 1.2825x; 1.2825x over previous
//
#include <hip/hip_runtime.h>
#include <hip/hip_bf16.h>
#include <stdint.h>

// Problem constants: B=2, S=1024 -> T=2048; D=1024; E=8; F=4*D=4096
#define DDIM 1024
#define EXP 8
#define FDIM 4096

typedef __attribute__((ext_vector_type(8))) short short8v;
typedef __attribute__((ext_vector_type(8))) short bf16x8;
typedef __attribute__((ext_vector_type(4))) float f32x4;

__device__ __forceinline__ unsigned short f2bf(float f) {
    unsigned u = __float_as_uint(f);
    u += 0x7FFFu + ((u >> 16) & 1u);          // round-to-nearest-even
    return (unsigned short)(u >> 16);
}
__device__ __forceinline__ float bf2f(unsigned short h) {
    return __uint_as_float(((unsigned)h) << 16);
}

// ---------------------------------------------------------------------------
// Packed operand format (R x K fp32 -> hi/lo bf16), tile = 128 rows x 32 k
// = 16 KiB. Row-local rl: 128B row of 8 16B slots. Logical slot l: 0-3 = hi
// k8-groups, 4-7 = lo. Stored slot s = l ^ (rl&7)  (XOR bank swizzle; GEMM
// ds_read_b128 lands 2-way max = free, m136). Tile linear bytes == the LDS
// image global_load_lds produces (identity map).
// Pack kernels iterate over STORED slots so global writes are coalesced.
// ---------------------------------------------------------------------------

// Pack x [T][D] -> Xp. One thread per stored 16B slot.
__global__ __launch_bounds__(256) void packx_kernel(
    const float* __restrict__ x, char* __restrict__ Xp, int T)
{
    int gi = blockIdx.x * 256 + threadIdx.x;   // slot index over T*256
    if (gi >= T * 256) return;
    int r = gi >> 8, rem = gi & 255;
    int kb = rem >> 3, s = rem & 7;            // k-tile, stored slot
    int l = s ^ (r & 7);                       // logical slot
    int k8 = (kb << 2) + (l & 3);              // k8-group within row
    bool lo = (l & 4) != 0;
    const float* src = x + (size_t)r * DDIM + k8 * 8;
    float4 v0 = *(const float4*)src;
    float4 v1 = *(const float4*)(src + 4);
    float f[8] = {v0.x, v0.y, v0.z, v0.w, v1.x, v1.y, v1.z, v1.w};
    short8v o;
#pragma unroll
    for (int i = 0; i < 8; ++i) {
        unsigned short hh = f2bf(f[i]);
        o[i] = lo ? (short)f2bf(f[i] - bf2f(hh)) : (short)hh;
    }
    size_t tb = ((size_t)((r >> 7) * (DDIM >> 5) + kb)) << 14;
    *(short8v*)(Xp + tb + ((r & 127) << 7) + (s << 4)) = o;   // coalesced
}

// Pack+transpose W [E][K][N] (k-major) -> Wp per expert as B-format [N][K].
// grid (Ktiles, Ntiles, E); one block per 32k x 128n tile.
__global__ __launch_bounds__(256) void packw_kernel(
    const float* __restrict__ W, char* __restrict__ Wp, int K, int N)
{
    int kb = blockIdx.x, nb = blockIdx.y, e = blockIdx.z;
    int t = threadIdx.x;
    int Ktiles = K >> 5;
    __shared__ float lds[32][132];             // pad 132: 16B-aligned float4 rows
    const float* src = W + (size_t)e * K * N + (size_t)(kb * 32) * N + nb * 128;
#pragma unroll
    for (int j = 0; j < 4; ++j) {
        int idx = t + j * 256;
        int kk = idx >> 5, c4 = idx & 31;      // 32 float4 per 128-wide row
        float4 v = *(const float4*)(src + (size_t)kk * N + c4 * 4);
        *(float4*)&lds[kk][c4 * 4] = v;
    }
    __syncthreads();
    char* tile = Wp + (size_t)e * ((size_t)N * K * 4)
               + (((size_t)(nb * Ktiles + kb)) << 14);
#pragma unroll
    for (int it = 0; it < 4; ++it) {
        int gi = it * 256 + t;                 // 0..1023 stored slots
        int n = gi >> 3, s = gi & 7;
        int l = s ^ (n & 7);
        int k8 = l & 3;
        bool lo = (l & 4) != 0;
        short8v o;
#pragma unroll
        for (int i = 0; i < 8; ++i) {
            float f = lds[k8 * 8 + i][n];
            unsigned short hh = f2bf(f);
            o[i] = lo ? (short)f2bf(f - bf2f(hh)) : (short)hh;
        }
        *(short8v*)(tile + (n << 7) + (s << 4)) = o;   // wave: 1KB contiguous
    }
}

// ---------------------------------------------------------------------------
// Router: logits + alpha-entmax(1.5) bisection + threshold. One block/token.
// (numerics identical to R3/R5 — keep absmax reproducible)
// ---------------------------------------------------------------------------
__global__ __launch_bounds__(256) void router_kernel(
    const float* __restrict__ x, const float* __restrict__ Wr,
    const float* __restrict__ br, float* __restrict__ gates)
{
    const int t = blockIdx.x;
    const int tid = threadIdx.x;
    const float* xr = x + (size_t)t * DDIM;

    float acc[EXP];
#pragma unroll
    for (int e = 0; e < EXP; ++e) acc[e] = 0.f;
    for (int d = tid; d < DDIM; d += 256) {
        float xv = xr[d];
        const float* wr = Wr + (size_t)d * EXP;
#pragma unroll
        for (int e = 0; e < EXP; ++e) acc[e] += xv * wr[e];
    }
#pragma unroll
    for (int e = 0; e < EXP; ++e) {
        float v = acc[e];
#pragma unroll
        for (int off = 32; off > 0; off >>= 1) v += __shfl_down(v, off);
        acc[e] = v;
    }
    __shared__ float part[4][EXP];
    const int wave = tid >> 6, lane = tid & 63;
    if (lane == 0) {
#pragma unroll
        for (int e = 0; e < EXP; ++e) part[wave][e] = acc[e];
    }
    __syncthreads();

    if (tid == 0) {
        float Xs[EXP];
        float mx = -1e30f;
#pragma unroll
        for (int e = 0; e < EXP; ++e) {
            float lg = part[0][e] + part[1][e] + part[2][e] + part[3][e] + br[e];
            Xs[e] = 0.5f * lg;                          // *(alpha-1), TEMP=1
            mx = fmaxf(mx, Xs[e]);
        }
        float tau_lo = mx - 1.0f;
        const float tau_hi = mx - 0.35355339059327373f; // (1/8)^0.5
        float f_lo = -1.0f;
#pragma unroll
        for (int e = 0; e < EXP; ++e) {
            float u = fmaxf(Xs[e] - tau_lo, 0.f);
            f_lo += u * u;                              // inv_am1 = 2
        }
        float dm = tau_hi - tau_lo;
        float tau_m = tau_lo;
        for (int it = 0; it < 25; ++it) {
            dm *= 0.5f;
            tau_m = tau_lo + dm;
            float f_m = -1.0f;
#pragma unroll
            for (int e = 0; e < EXP; ++e) {
                float u = fmaxf(Xs[e] - tau_m, 0.f);
                f_m += u * u;
            }
            if (f_m * f_lo >= 0.f) tau_lo = tau_m;
        }
        float p[EXP], s = 0.f;
#pragma unroll
        for (int e = 0; e < EXP; ++e) {
            float u = fmaxf(Xs[e] - tau_m, 0.f);
            p[e] = u * u;
            s += p[e];
        }
        float inv = 1.f / s;
#pragma unroll
        for (int e = 0; e < EXP; ++e) {
            float g = p[e] * inv;
            gates[(size_t)t * EXP + e] = (g > 1e-9f) ? g : 0.f;
        }
    }
}

// ---------------------------------------------------------------------------
// Packed-operand split-bf16 MFMA GEMM, 2-phase double-buffered (T3 minimum
// recipe): per K-step {frag ds_reads(cur) -> STAGE(cur^1,kb+1) -> 48 MFMA ->
// barrier}. Stage latency hides under the MFMA cluster; one barrier/step.
// 128x128 tile, BK=32, 4 waves (2x2), wave-tile 64x64, 3 MFMA products.
// EPI=1: H = split(relu(C+b1)*gate) in packed-A format. EPI=2: P fp32.
// ---------------------------------------------------------------------------
template<int EPI>
__global__ __launch_bounds__(256) void gemm_pk(
    const char* __restrict__ Ap, size_t a_es, int arb0,
    const char* __restrict__ Bp, size_t b_es,
    int Ktiles, int Mb, int Nb,
    const float* __restrict__ bias, const float* __restrict__ gates,
    char* __restrict__ Hout, float* __restrict__ Pout,
    int CT, int t0)
{
    __shared__ char sA[2][16384];
    __shared__ char sB[2][16384];

    const int tid = threadIdx.x;
    const int lane = tid & 63;
    const int wid = tid >> 6;
    const int wr = wid >> 1, wc = wid & 1;
    const int lr = lane & 15, lg = lane >> 4;
    const int rx = lr & 7;

    // bijective XCD swizzle (nwg always a multiple of 8)
    int bI = blockIdx.x;
    int nwg = Mb * Nb * EXP;
    int cpx = nwg >> 3;
    int w = (bI & 7) * cpx + (bI >> 3);
    int e = w / (Mb * Nb);
    int rem = w - e * (Mb * Nb);
    int mb, nb;
    if (EPI == 1) { nb = rem / Mb; mb = rem - nb * Mb; }   // mb fastest: share B panel
    else          { mb = rem / Nb; nb = rem - mb * Nb; }   // nb fastest: share A panel

    const char* Abase = Ap + (size_t)e * a_es + (((size_t)(arb0 + mb) * Ktiles) << 14);
    const char* Bbase = Bp + (size_t)e * b_es + (((size_t)nb * Ktiles) << 14);

    f32x4 acc[4][4];
#pragma unroll
    for (int mi = 0; mi < 4; ++mi)
#pragma unroll
        for (int ni = 0; ni < 4; ++ni) acc[mi][ni] = (f32x4){0.f, 0.f, 0.f, 0.f};

    // fragment byte offsets (hi plane); lo plane = ^64
    int aoff[4], boff[4];
#pragma unroll
    for (int mi = 0; mi < 4; ++mi)
        aoff[mi] = (wr * 64 + mi * 16 + lr) * 128 + ((lg ^ rx) << 4);
#pragma unroll
    for (int ni = 0; ni < 4; ++ni)
        boff[ni] = (wc * 64 + ni * 16 + lr) * 128 + ((lg ^ rx) << 4);

    const int stg  = (wid << 12) + (lane << 4);   // per-lane global src offset
    const int ldst = wid << 12;                   // wave-uniform LDS dest

    bf16x8 ah[4], al[4], bh[4], bl[4];

    auto stage = [&](int buf, int kb) {
        const char* at = Abase + ((size_t)kb << 14) + stg;
        const char* bt = Bbase + ((size_t)kb << 14) + stg;
        char* da = &sA[buf][0] + ldst;
        char* db = &sB[buf][0] + ldst;
#pragma unroll
        for (int j = 0; j < 4; ++j) {
            __builtin_amdgcn_global_load_lds(
                (const __attribute__((address_space(1))) void*)(at + j * 1024),
                (__attribute__((address_space(3))) void*)(da + j * 1024),
                16, 0, 0);
            __builtin_amdgcn_global_load_lds(
                (const __attribute__((address_space(1))) void*)(bt + j * 1024),
                (__attribute__((address_space(3))) void*)(db + j * 1024),
                16, 0, 0);
        }
    };
    auto frag_load = [&](int buf) {
        const char* pa = &sA[buf][0];
        const char* pb = &sB[buf][0];
#pragma unroll
        for (int mi = 0; mi < 4; ++mi) {
            ah[mi] = *(const bf16x8*)(pa + aoff[mi]);
            al[mi] = *(const bf16x8*)(pa + (aoff[mi] ^ 64));
        }
#pragma unroll
        for (int ni = 0; ni < 4; ++ni) {
            bh[ni] = *(const bf16x8*)(pb + boff[ni]);
            bl[ni] = *(const bf16x8*)(pb + (boff[ni] ^ 64));
        }
    };
    auto do_mfma = [&]() {
#pragma unroll
        for (int ni = 0; ni < 4; ++ni)
#pragma unroll
            for (int mi = 0; mi < 4; ++mi) {
                acc[mi][ni] = __builtin_amdgcn_mfma_f32_16x16x32_bf16(ah[mi], bh[ni], acc[mi][ni], 0, 0, 0);
                acc[mi][ni] = __builtin_amdgcn_mfma_f32_16x16x32_bf16(ah[mi], bl[ni], acc[mi][ni], 0, 0, 0);
                acc[mi][ni] = __builtin_amdgcn_mfma_f32_16x16x32_bf16(al[mi], bh[ni], acc[mi][ni], 0, 0, 0);
            }
    };

    stage(0, 0);
    __syncthreads();                 // compiler drains vmcnt(0): buf0 ready
    int cur = 0;
    for (int kb = 0; kb < Ktiles - 1; ++kb) {
        frag_load(cur);              // ds_reads of current tile
        stage(cur ^ 1, kb + 1);      // prefetch next tile (in flight under MFMA)
        do_mfma();
        __syncthreads();             // drains vmcnt(0)+lgkm: next buf ready, cur reusable
        cur ^= 1;
    }
    frag_load(cur);
    do_mfma();

    const int m0 = mb * 128, n0 = nb * 128;
    // C/D layout (m89-verified): col = lane&15, row = (lane>>4)*4 + reg.
    if (EPI == 1) {
        char* He = Hout + (size_t)e * ((size_t)CT * FDIM * 4);
        float garr[4][4];
#pragma unroll
        for (int mi = 0; mi < 4; ++mi)
#pragma unroll
            for (int r = 0; r < 4; ++r)
                garr[mi][r] = gates[(size_t)(t0 + m0 + wr * 64 + mi * 16 + lg * 4 + r) * EXP + e];
#pragma unroll
        for (int ni = 0; ni < 4; ++ni) {
            const int f = n0 + wc * 64 + ni * 16 + lr;
            const float bv = bias[e * FDIM + f];
            const int fb = f >> 5, kl = f & 31;
#pragma unroll
            for (int mi = 0; mi < 4; ++mi) {
#pragma unroll
                for (int r = 0; r < 4; ++r) {
                    int mrow = m0 + wr * 64 + mi * 16 + lg * 4 + r;
                    float v = fmaxf(acc[mi][ni][r] + bv, 0.f) * garr[mi][r];
                    unsigned short hh = f2bf(v);
                    unsigned short ll = f2bf(v - bf2f(hh));
                    int rl = mrow & 127;
                    size_t tb = ((size_t)((mrow >> 7) * (FDIM >> 5) + fb)) << 14;
                    char* pa = He + tb + (rl << 7) + ((kl & 7) << 1);
                    int sh = (((kl >> 3) ^ (rl & 7)) << 4);
                    *(unsigned short*)(pa + sh) = hh;
                    *(unsigned short*)(pa + (sh ^ 64)) = ll;
                }
            }
        }
    } else {
#pragma unroll
        for (int mi = 0; mi < 4; ++mi) {
#pragma unroll
            for (int ni = 0; ni < 4; ++ni) {
                const int col = n0 + wc * 64 + ni * 16 + lr;
#pragma unroll
                for (int r = 0; r < 4; ++r) {
                    int mrow = m0 + wr * 64 + mi * 16 + lg * 4 + r;
                    Pout[((size_t)e * CT + mrow) * DDIM + col] = acc[mi][ni][r];
                }
            }
        }
    }
}

// ---------------------------------------------------------------------------
// out[t0+m][d] = sum_e ( P[e][m][d] + gate[t][e]*b2[e][d] )
// ---------------------------------------------------------------------------
__global__ __launch_bounds__(256) void reduce_kernel(
    const float* __restrict__ P, const float* __restrict__ gates,
    const float* __restrict__ b2, float* __restrict__ out, int t0, int CT)
{
    int i = blockIdx.x * 256 + threadIdx.x;    // float4 idx within chunk
    int m = i >> 8, d4 = i & 255;              // DDIM/4 = 256
    if (m >= CT) return;
    int t = t0 + m;
    float4 s = {0.f, 0.f, 0.f, 0.f};
#pragma unroll
    for (int e = 0; e < EXP; ++e) {
        float g = gates[(size_t)t * EXP + e];
        float4 p = ((const float4*)P)[((size_t)e * CT + m) * 256 + d4];
        float4 bb = ((const float4*)b2)[e * 256 + d4];
        s.x += p.x + g * bb.x;
        s.y += p.y + g * bb.y;
        s.z += p.z + g * bb.z;
        s.w += p.w + g * bb.w;
    }
    ((float4*)out)[(size_t)t * 256 + d4] = s;
}

// ---------------------------------------------------------------------------
extern "C" void kernel_launch(void* const* d_in, const int* in_sizes, int n_in,
                              void* d_out, int out_size, void* d_ws, size_t ws_size,
                              hipStream_t stream)
{
    const float* x  = (const float*)d_in[0];
    const float* Wr = (const float*)d_in[1];
    const float* br = (const float*)d_in[2];
    const float* W1 = (const float*)d_in[3];
    const float* b1 = (const float*)d_in[4];
    const float* W2 = (const float*)d_in[5];
    const float* b2 = (const float*)d_in[6];
    float* out = (float*)d_out;

    const int T = in_sizes[0] / DDIM;   // 2048

    char* p = (char*)d_ws;
    size_t used = 0;
    auto carve = [&](size_t bytes) {
        char* r = p + used;
        used += (bytes + 255) & ~(size_t)255;
        return r;
    };
    float* gates = (float*)carve((size_t)T * EXP * 4);
    char*  Xp    = carve((size_t)T * DDIM * 4);
    char*  W1p   = carve((size_t)EXP * DDIM * FDIM * 4);
    char*  W2p   = carve((size_t)EXP * FDIM * DDIM * 4);

    const size_t per_tok = (size_t)EXP * FDIM * 4 + (size_t)EXP * DDIM * 4;
    int CT = 128;
    for (int c = 2048; c >= 128; c >>= 1)
        if (used + (size_t)c * per_tok + 1024 <= ws_size) { CT = c; break; }
    if (CT > T) CT = T;
    char*  Hp = carve((size_t)EXP * CT * FDIM * 4);
    float* Pp = (float*)carve((size_t)EXP * CT * DDIM * 4);

    // ---- pack passes ----
    packx_kernel<<<dim3(T), dim3(256), 0, stream>>>(x, Xp, T);
    packw_kernel<<<dim3(DDIM / 32, FDIM / 128, EXP), dim3(256), 0, stream>>>(W1, W1p, DDIM, FDIM);
    packw_kernel<<<dim3(FDIM / 32, DDIM / 128, EXP), dim3(256), 0, stream>>>(W2, W2p, FDIM, DDIM);
    router_kernel<<<dim3(T), dim3(256), 0, stream>>>(x, Wr, br, gates);

    const size_t w_es = (size_t)DDIM * FDIM * 4;   // 16 MiB per expert (both W)
    for (int t0 = 0; t0 < T; t0 += CT) {
        int Mb = CT / 128;
        // GEMM1: A=Xp (R=T,K=D), B=W1p (R=F,K=D) -> H packed
        gemm_pk<1><<<dim3(Mb * (FDIM / 128) * EXP), dim3(256), 0, stream>>>(
            Xp, (size_t)0, t0 >> 7, W1p, w_es, DDIM / 32, Mb, FDIM / 128,
            b1, gates, Hp, (float*)nullptr, CT, t0);
        // GEMM2: A=Hp (R=CT,K=F per expert), B=W2p (R=D,K=F) -> P fp32
        gemm_pk<2><<<dim3(Mb * (DDIM / 128) * EXP), dim3(256), 0, stream>>>(
            Hp, (size_t)CT * FDIM * 4, 0, W2p, w_es, FDIM / 32, Mb, DDIM / 128,
            (const float*)nullptr, gates, (char*)nullptr, Pp, CT, t0);
        reduce_kernel<<<dim3(CT), dim3(256), 0, stream>>>(Pp, gates, b2, out, t0, CT);
    }
}